// Round 3
// baseline (251.569 us; speedup 1.0000x reference)
//
#include <hip/hip_runtime.h>
#include <stdint.h>

#define BB 8
#define CC 8
#define HH 512
#define WW 512
#define HWSZ (HH * WW)

typedef float v4 __attribute__((ext_vector_type(4)));

#define LOG2_CLAMP -144.26950409f   // -100 / ln2

__device__ __forceinline__ v4 uload4(const float* __restrict__ p) {
    v4 r;
    __builtin_memcpy(&r, p, sizeof(v4));   // 4B-aligned dwordx4
    return r;
}
__device__ __forceinline__ v4 aload4(const float* __restrict__ p) {
    return *(const v4* __restrict__)p;
}

__device__ __forceinline__ v4 sig4(v4 x) {
    v4 r;
#pragma unroll
    for (int i = 0; i < 4; ++i)
        r[i] = __builtin_amdgcn_rcpf(1.0f + __expf(-x[i]));
    return r;
}

// One branch: cr = center ch 0..7, nr = neighbor for vote k, sel = con bitmask,
// mkA/B/C = border masks for elem {0, 1-2, 3}. Accumulates POSITIVE log2 sums.
template <bool NEED_MIN>
__device__ __forceinline__ void eval_branch(
    const v4* __restrict__ cr, const v4* __restrict__ nr, uint32_t sel,
    const float* __restrict__ mkA, const float* __restrict__ mkB,
    const float* __restrict__ mkC,
    v4& glo, v4& vmin, float& Lbic, float& Lcon)
{
    const v4 one = {1.f, 1.f, 1.f, 1.f};
    v4 pb0 = one, pb1 = one, pc = one;
    v4 vsum = {0.f, 0.f, 0.f, 0.f};
    if (NEED_MIN) vmin = {1e30f, 1e30f, 1e30f, 1e30f};

#pragma unroll
    for (int k = 0; k < 8; ++k) {
        v4 s = sig4(cr[k]);
        v4 n = sig4(nr[k]);
        n[0] *= mkA[k]; n[1] *= mkB[k]; n[2] *= mkB[k]; n[3] *= mkC[k];
        v4 v = s * n;
        vsum += v;
        if (NEED_MIN) vmin = __builtin_elementwise_min(vmin, v);
        v4 av, as;
#pragma unroll
        for (int i = 0; i < 4; ++i) {
            const bool bt = (sel >> (k * 4 + i)) & 1u;
            av[i] = bt ? v[i] : 1.0f - v[i];
            as[i] = bt ? s[i] : 1.0f - s[i];
        }
        if (k < 4) pb0 *= av; else pb1 *= av;
        pc *= as;
    }
    glo = vsum * 0.125f;

    float lb = 0.f, lc = 0.f;
#pragma unroll
    for (int i = 0; i < 4; ++i) {
        lb += fmaxf(__log2f(pb0[i]), LOG2_CLAMP) + fmaxf(__log2f(pb1[i]), LOG2_CLAMP);
        lc += fmaxf(__log2f(pc[i]), LOG2_CLAMP);
    }
    Lbic = lb;
    Lcon = lc;
}

__global__ __launch_bounds__(256, 4) void bicon_loss_kernel(
    const float* __restrict__ atts, const float* __restrict__ dets,
    const float* __restrict__ target, const float* __restrict__ con,
    float* __restrict__ out)
{
    // XCD-chunked swizzle (2048 % 8 == 0, bijective): each XCD gets one batch
    // image's worth of contiguous rows -> vertical halo re-reads are L2-local.
    const int nchunk = (int)gridDim.x >> 3;
    const int bid = ((int)blockIdx.x & 7) * nchunk + ((int)blockIdx.x >> 3);

    const int idx = bid * 256 + (int)threadIdx.x;     // 4-pixel group
    const int w0  = (idx & 127) << 2;
    const int row = idx >> 7;                         // b*H + h
    const int h   = row & (HH - 1);
    const int b   = row >> 9;

    const int hm = (h > 0) ? h - 1 : 0;
    const int hp = (h < HH - 1) ? h + 1 : HH - 1;
    const float mh0 = (h > 0) ? 1.0f : 0.0f;
    const float mh1 = (h < HH - 1) ? 1.0f : 0.0f;
    const float mw0 = (w0 == 0) ? 0.0f : 1.0f;
    const float mw3 = (w0 == WW - 4) ? 0.0f : 1.0f;

    const int offC = h * WW + w0;
    const int offU = hm * WW + w0;
    const int offD = hp * WW + w0;

    const float* __restrict__ ab = atts + b * CC * HWSZ;
    const float* __restrict__ db = dets + b * CC * HWSZ;
    const float* __restrict__ cb = con  + b * CC * HWSZ;

    // ---- loads issued in CONSUMPTION order (in-order vmcnt => no head-of-line
    // blocking): con/target (sel needed at k=0 of both branches), atts, dets ----
    v4 cvv[8];
#pragma unroll
    for (int c = 0; c < 8; ++c) cvv[c] = aload4(cb + c * HWSZ + offC);
    v4 tv = aload4(target + b * HWSZ + offC);

    v4 ac[8], an[8];
#pragma unroll
    for (int c = 0; c < 8; ++c) ac[c] = aload4(ab + c * HWSZ + offC);
    an[0] = uload4(ab + 7 * HWSZ + offU - 1);
    an[1] = aload4(ab + 6 * HWSZ + offU);
    an[2] = uload4(ab + 5 * HWSZ + offU + 1);
    an[3] = uload4(ab + 4 * HWSZ + offC - 1);
    an[4] = uload4(ab + 3 * HWSZ + offC + 1);
    an[5] = uload4(ab + 2 * HWSZ + offD - 1);
    an[6] = aload4(ab + 1 * HWSZ + offD);
    an[7] = uload4(ab + 0 * HWSZ + offD + 1);

    // con/target -> bitmasks (frees ~36 VGPRs before the dets loads need them)
    uint32_t sel = 0u;
#pragma unroll
    for (int c = 0; c < 8; ++c)
#pragma unroll
        for (int i = 0; i < 4; ++i)
            if (cvv[c][i] > 0.5f) sel |= (1u << (c * 4 + i));
    uint32_t tb = 0u;
#pragma unroll
    for (int i = 0; i < 4; ++i)
        if (tv[i] > 0.5f) tb |= (1u << i);

    v4 dc[8], dn[8];
#pragma unroll
    for (int c = 0; c < 8; ++c) dc[c] = aload4(db + c * HWSZ + offC);
    dn[0] = uload4(db + 7 * HWSZ + offU - 1);
    dn[1] = aload4(db + 6 * HWSZ + offU);
    dn[2] = uload4(db + 5 * HWSZ + offU + 1);
    dn[3] = uload4(db + 4 * HWSZ + offC - 1);
    dn[4] = uload4(db + 3 * HWSZ + offC + 1);
    dn[5] = uload4(db + 2 * HWSZ + offD - 1);
    dn[6] = aload4(db + 1 * HWSZ + offD);
    dn[7] = uload4(db + 0 * HWSZ + offD + 1);

    const float mkA[8] = {mh0 * mw0, mh0, mh0,       mw0, 1.f, mh1 * mw0, mh1, mh1};
    const float mkB[8] = {mh0,       mh0, mh0,       1.f, 1.f, mh1,       mh1, mh1};
    const float mkC[8] = {mh0,       mh0, mh0 * mw3, 1.f, mw3, mh1,       mh1, mh1 * mw3};

    v4 glo1, glo2, vmin1, vmin2;
    float Lb1, Lc1, Lb2, Lc2;
    eval_branch<false>(ac, an, sel, mkA, mkB, mkC, glo1, vmin1, Lb1, Lc1);
    eval_branch<true >(dc, dn, sel, mkA, mkB, mkC, glo2, vmin2, Lb2, Lc2);

    // pixel-level: bce(glo1,t) + bce(dec,t), combined into one log
    float Lp = 0.f;
#pragma unroll
    for (int i = 0; i < 4; ++i) {
        const uint32_t mI    = 0x11111111u << i;
        const uint32_t bitsI = sel & mI;
        const bool edge = (bitsI != 0u) && (bitsI != mI);   // 0 < popcount < 8
        const float dec = edge ? (1.0f - vmin2[i]) : glo2[i];
        const bool  ti  = (tb >> i) & 1u;
        const float a   = ti ? glo1[i] : 1.0f - glo1[i];
        const float bs  = ti ? dec     : 1.0f - dec;
        Lp += fmaxf(__log2f(a * bs), LOG2_CLAMP);
    }

    const float wbic = 0.2f / (float)(BB * CC * HWSZ);
    const float wcon = 0.8f / (float)(BB * CC * HWSZ);
    const float wpix = 1.0f / (float)(BB * HWSZ);
    const float ln2  = 0.69314718056f;

    float local = -(wbic * (Lb1 + Lb2) + wcon * (Lc1 + Lc2) + wpix * Lp) * ln2;

#pragma unroll
    for (int off = 32; off > 0; off >>= 1)
        local += __shfl_down(local, off, 64);

    __shared__ float wsum[4];
    const int lane = threadIdx.x & 63;
    const int wid  = threadIdx.x >> 6;
    if (lane == 0) wsum[wid] = local;
    __syncthreads();
    if (threadIdx.x == 0) {
        atomicAdd(out, wsum[0] + wsum[1] + wsum[2] + wsum[3]);
    }
}

extern "C" void kernel_launch(void* const* d_in, const int* in_sizes, int n_in,
                              void* d_out, int out_size, void* d_ws, size_t ws_size,
                              hipStream_t stream) {
    const float* atts   = (const float*)d_in[0];
    const float* dets   = (const float*)d_in[1];
    const float* target = (const float*)d_in[2];
    const float* con    = (const float*)d_in[3];
    float* out = (float*)d_out;

    hipMemsetAsync(out, 0, sizeof(float), stream);

    const int ngroups = BB * HH * WW / 4;   // 524288 threads, 4 px each
    bicon_loss_kernel<<<ngroups / 256, 256, 0, stream>>>(atts, dets, target, con, out);
}

// Round 4
// 202.724 us; speedup vs baseline: 1.2409x; 1.2409x over previous
//
#include <hip/hip_runtime.h>
#include <stdint.h>

#define BB 8
#define CC 8
#define HH 512
#define WW 512
#define HWSZ (HH * WW)

typedef float v4 __attribute__((ext_vector_type(4)));

#define LOG2_CLAMP -144.26950409f   // -100 / ln2

__device__ __forceinline__ v4 uload4(const float* __restrict__ p) {
    v4 r;
    __builtin_memcpy(&r, p, sizeof(v4));   // 4B-aligned dwordx4
    return r;
}
__device__ __forceinline__ v4 aload4(const float* __restrict__ p) {
    return *(const v4* __restrict__)p;
}

__device__ __forceinline__ v4 sig4(v4 x) {
    v4 r;
#pragma unroll
    for (int i = 0; i < 4; ++i)
        r[i] = __builtin_amdgcn_rcpf(1.0f + __expf(-x[i]));
    return r;
}

// One branch: cr = center ch 0..7, nr = neighbor for vote k, sel = con bitmask,
// mkA/B/C = border masks for elem {0, 1-2, 3}. Accumulates POSITIVE log2 sums.
template <bool NEED_MIN>
__device__ __forceinline__ void eval_branch(
    const v4* __restrict__ cr, const v4* __restrict__ nr, uint32_t sel,
    const float* __restrict__ mkA, const float* __restrict__ mkB,
    const float* __restrict__ mkC,
    v4& glo, v4& vmin, float& Lbic, float& Lcon)
{
    const v4 one = {1.f, 1.f, 1.f, 1.f};
    v4 pb0 = one, pb1 = one, pc = one;
    v4 vsum = {0.f, 0.f, 0.f, 0.f};
    if (NEED_MIN) vmin = {1e30f, 1e30f, 1e30f, 1e30f};

#pragma unroll
    for (int k = 0; k < 8; ++k) {
        v4 s = sig4(cr[k]);
        v4 n = sig4(nr[k]);
        n[0] *= mkA[k]; n[1] *= mkB[k]; n[2] *= mkB[k]; n[3] *= mkC[k];
        v4 v = s * n;
        vsum += v;
        if (NEED_MIN) vmin = __builtin_elementwise_min(vmin, v);
        v4 av, as;
#pragma unroll
        for (int i = 0; i < 4; ++i) {
            const bool bt = (sel >> (k * 4 + i)) & 1u;
            av[i] = bt ? v[i] : 1.0f - v[i];
            as[i] = bt ? s[i] : 1.0f - s[i];
        }
        if (k < 4) pb0 *= av; else pb1 *= av;
        pc *= as;
    }
    glo = vsum * 0.125f;

    float lb = 0.f, lc = 0.f;
#pragma unroll
    for (int i = 0; i < 4; ++i) {
        lb += fmaxf(__log2f(pb0[i]), LOG2_CLAMP) + fmaxf(__log2f(pb1[i]), LOG2_CLAMP);
        lc += fmaxf(__log2f(pc[i]), LOG2_CLAMP);
    }
    Lbic = lb;
    Lcon = lc;
}

__global__ __launch_bounds__(256, 2) void bicon_loss_kernel(
    const float* __restrict__ atts, const float* __restrict__ dets,
    const float* __restrict__ target, const float* __restrict__ con,
    float* __restrict__ out)
{
    // default block order (no XCD swizzle: round-robin dispatch already
    // co-locates vertical-halo neighbor blocks per XCD; remap cost +11% FETCH)
    const int idx = (int)blockIdx.x * 256 + (int)threadIdx.x;  // 4-pixel group
    const int w0  = (idx & 127) << 2;
    const int row = idx >> 7;                         // b*H + h
    const int h   = row & (HH - 1);
    const int b   = row >> 9;

    const int hm = (h > 0) ? h - 1 : 0;
    const int hp = (h < HH - 1) ? h + 1 : HH - 1;
    const float mh0 = (h > 0) ? 1.0f : 0.0f;
    const float mh1 = (h < HH - 1) ? 1.0f : 0.0f;
    const float mw0 = (w0 == 0) ? 0.0f : 1.0f;
    const float mw3 = (w0 == WW - 4) ? 0.0f : 1.0f;

    const int offC = h * WW + w0;
    const int offU = hm * WW + w0;
    const int offD = hp * WW + w0;

    const float* __restrict__ ab = atts + b * CC * HWSZ;
    const float* __restrict__ db = dets + b * CC * HWSZ;
    const float* __restrict__ cb = con  + b * CC * HWSZ;

    // ---- loads in CONSUMPTION order: con/target (needed at k=0 of branch-a),
    // then atts (branch-a), then dets (branch-b). In-order vmcnt => branch-a
    // compute can start while the 16 dets loads are still in flight. ----
    v4 cvv[8];
#pragma unroll
    for (int c = 0; c < 8; ++c) cvv[c] = aload4(cb + c * HWSZ + offC);
    v4 tv = aload4(target + b * HWSZ + offC);

    v4 ac[8], an[8];
#pragma unroll
    for (int c = 0; c < 8; ++c) ac[c] = aload4(ab + c * HWSZ + offC);
    an[0] = uload4(ab + 7 * HWSZ + offU - 1);
    an[1] = aload4(ab + 6 * HWSZ + offU);
    an[2] = uload4(ab + 5 * HWSZ + offU + 1);
    an[3] = uload4(ab + 4 * HWSZ + offC - 1);
    an[4] = uload4(ab + 3 * HWSZ + offC + 1);
    an[5] = uload4(ab + 2 * HWSZ + offD - 1);
    an[6] = aload4(ab + 1 * HWSZ + offD);
    an[7] = uload4(ab + 0 * HWSZ + offD + 1);

    v4 dc[8], dn[8];
#pragma unroll
    for (int c = 0; c < 8; ++c) dc[c] = aload4(db + c * HWSZ + offC);
    dn[0] = uload4(db + 7 * HWSZ + offU - 1);
    dn[1] = aload4(db + 6 * HWSZ + offU);
    dn[2] = uload4(db + 5 * HWSZ + offU + 1);
    dn[3] = uload4(db + 4 * HWSZ + offC - 1);
    dn[4] = uload4(db + 3 * HWSZ + offC + 1);
    dn[5] = uload4(db + 2 * HWSZ + offD - 1);
    dn[6] = aload4(db + 1 * HWSZ + offD);
    dn[7] = uload4(db + 0 * HWSZ + offD + 1);

    // con/target -> bitmasks (only waits on the FIRST 9 loads)
    uint32_t sel = 0u;
#pragma unroll
    for (int c = 0; c < 8; ++c)
#pragma unroll
        for (int i = 0; i < 4; ++i)
            if (cvv[c][i] > 0.5f) sel |= (1u << (c * 4 + i));
    uint32_t tb = 0u;
#pragma unroll
    for (int i = 0; i < 4; ++i)
        if (tv[i] > 0.5f) tb |= (1u << i);

    const float mkA[8] = {mh0 * mw0, mh0, mh0,       mw0, 1.f, mh1 * mw0, mh1, mh1};
    const float mkB[8] = {mh0,       mh0, mh0,       1.f, 1.f, mh1,       mh1, mh1};
    const float mkC[8] = {mh0,       mh0, mh0 * mw3, 1.f, mw3, mh1,       mh1, mh1 * mw3};

    v4 glo1, glo2, vmin1, vmin2;
    float Lb1, Lc1, Lb2, Lc2;
    eval_branch<false>(ac, an, sel, mkA, mkB, mkC, glo1, vmin1, Lb1, Lc1);
    eval_branch<true >(dc, dn, sel, mkA, mkB, mkC, glo2, vmin2, Lb2, Lc2);

    // pixel-level: bce(glo1,t) + bce(dec,t), combined into one log
    float Lp = 0.f;
#pragma unroll
    for (int i = 0; i < 4; ++i) {
        const uint32_t mI    = 0x11111111u << i;
        const uint32_t bitsI = sel & mI;
        const bool edge = (bitsI != 0u) && (bitsI != mI);   // 0 < popcount < 8
        const float dec = edge ? (1.0f - vmin2[i]) : glo2[i];
        const bool  ti  = (tb >> i) & 1u;
        const float a   = ti ? glo1[i] : 1.0f - glo1[i];
        const float bs  = ti ? dec     : 1.0f - dec;
        Lp += fmaxf(__log2f(a * bs), LOG2_CLAMP);
    }

    const float wbic = 0.2f / (float)(BB * CC * HWSZ);
    const float wcon = 0.8f / (float)(BB * CC * HWSZ);
    const float wpix = 1.0f / (float)(BB * HWSZ);
    const float ln2  = 0.69314718056f;

    float local = -(wbic * (Lb1 + Lb2) + wcon * (Lc1 + Lc2) + wpix * Lp) * ln2;

#pragma unroll
    for (int off = 32; off > 0; off >>= 1)
        local += __shfl_down(local, off, 64);

    __shared__ float wsum[4];
    const int lane = threadIdx.x & 63;
    const int wid  = threadIdx.x >> 6;
    if (lane == 0) wsum[wid] = local;
    __syncthreads();
    if (threadIdx.x == 0) {
        atomicAdd(out, wsum[0] + wsum[1] + wsum[2] + wsum[3]);
    }
}

extern "C" void kernel_launch(void* const* d_in, const int* in_sizes, int n_in,
                              void* d_out, int out_size, void* d_ws, size_t ws_size,
                              hipStream_t stream) {
    const float* atts   = (const float*)d_in[0];
    const float* dets   = (const float*)d_in[1];
    const float* target = (const float*)d_in[2];
    const float* con    = (const float*)d_in[3];
    float* out = (float*)d_out;

    hipMemsetAsync(out, 0, sizeof(float), stream);

    const int ngroups = BB * HH * WW / 4;   // 524288 threads, 4 px each
    bicon_loss_kernel<<<ngroups / 256, 256, 0, stream>>>(atts, dets, target, con, out);
}

// Round 5
// 202.505 us; speedup vs baseline: 1.2423x; 1.0011x over previous
//
#include <hip/hip_runtime.h>
#include <stdint.h>

#define BB 8
#define CC 8
#define HH 512
#define WW 512
#define HWSZ (HH * WW)

typedef float v4 __attribute__((ext_vector_type(4)));

#define LOG2_CLAMP -144.26950409f   // -100 / ln2

__device__ __forceinline__ v4 uload4(const float* __restrict__ p) {
    v4 r;
    __builtin_memcpy(&r, p, sizeof(v4));   // 4B-aligned dwordx4
    return r;
}
__device__ __forceinline__ v4 aload4(const float* __restrict__ p) {
    return *(const v4* __restrict__)p;
}

__device__ __forceinline__ v4 sig4(v4 x) {
    v4 r;
#pragma unroll
    for (int i = 0; i < 4; ++i)
        r[i] = __builtin_amdgcn_rcpf(1.0f + __expf(-x[i]));
    return r;
}

// One branch: cr = center ch 0..7, nr = neighbor for vote k, sel = con bitmask,
// mkA/B/C = border masks for elem {0, 1-2, 3}. Accumulates POSITIVE log2 sums.
template <bool NEED_MIN>
__device__ __forceinline__ void eval_branch(
    const v4* __restrict__ cr, const v4* __restrict__ nr, uint32_t sel,
    const float* __restrict__ mkA, const float* __restrict__ mkB,
    const float* __restrict__ mkC,
    v4& glo, v4& vmin, float& Lbic, float& Lcon)
{
    const v4 one = {1.f, 1.f, 1.f, 1.f};
    v4 pb0 = one, pb1 = one, pc = one;
    v4 vsum = {0.f, 0.f, 0.f, 0.f};
    if (NEED_MIN) vmin = {1e30f, 1e30f, 1e30f, 1e30f};

#pragma unroll
    for (int k = 0; k < 8; ++k) {
        v4 s = sig4(cr[k]);
        v4 n = sig4(nr[k]);
        n[0] *= mkA[k]; n[1] *= mkB[k]; n[2] *= mkB[k]; n[3] *= mkC[k];
        v4 v = s * n;
        vsum += v;
        if (NEED_MIN) vmin = __builtin_elementwise_min(vmin, v);
        v4 av, as;
#pragma unroll
        for (int i = 0; i < 4; ++i) {
            const bool bt = (sel >> (k * 4 + i)) & 1u;
            av[i] = bt ? v[i] : 1.0f - v[i];
            as[i] = bt ? s[i] : 1.0f - s[i];
        }
        if (k < 4) pb0 *= av; else pb1 *= av;
        pc *= as;
    }
    glo = vsum * 0.125f;

    float lb = 0.f, lc = 0.f;
#pragma unroll
    for (int i = 0; i < 4; ++i) {
        lb += fmaxf(__log2f(pb0[i]), LOG2_CLAMP) + fmaxf(__log2f(pb1[i]), LOG2_CLAMP);
        lc += fmaxf(__log2f(pc[i]), LOG2_CLAMP);
    }
    Lbic = lb;
    Lcon = lc;
}

__global__ __launch_bounds__(256, 2) void bicon_loss_kernel(
    const float* __restrict__ atts, const float* __restrict__ dets,
    const float* __restrict__ target, const float* __restrict__ con,
    float* __restrict__ partial)
{
    const int idx = (int)blockIdx.x * 256 + (int)threadIdx.x;  // 4-pixel group
    const int w0  = (idx & 127) << 2;
    const int row = idx >> 7;                         // b*H + h
    const int h   = row & (HH - 1);
    const int b   = row >> 9;

    const int hm = (h > 0) ? h - 1 : 0;
    const int hp = (h < HH - 1) ? h + 1 : HH - 1;
    const float mh0 = (h > 0) ? 1.0f : 0.0f;
    const float mh1 = (h < HH - 1) ? 1.0f : 0.0f;
    const float mw0 = (w0 == 0) ? 0.0f : 1.0f;
    const float mw3 = (w0 == WW - 4) ? 0.0f : 1.0f;

    const int offC = h * WW + w0;
    const int offU = hm * WW + w0;
    const int offD = hp * WW + w0;

    const float* __restrict__ ab = atts + b * CC * HWSZ;
    const float* __restrict__ db = dets + b * CC * HWSZ;
    const float* __restrict__ cb = con  + b * CC * HWSZ;

    v4 cvv[8];
#pragma unroll
    for (int c = 0; c < 8; ++c) cvv[c] = aload4(cb + c * HWSZ + offC);
    v4 tv = aload4(target + b * HWSZ + offC);

    v4 ac[8], an[8];
#pragma unroll
    for (int c = 0; c < 8; ++c) ac[c] = aload4(ab + c * HWSZ + offC);
    an[0] = uload4(ab + 7 * HWSZ + offU - 1);
    an[1] = aload4(ab + 6 * HWSZ + offU);
    an[2] = uload4(ab + 5 * HWSZ + offU + 1);
    an[3] = uload4(ab + 4 * HWSZ + offC - 1);
    an[4] = uload4(ab + 3 * HWSZ + offC + 1);
    an[5] = uload4(ab + 2 * HWSZ + offD - 1);
    an[6] = aload4(ab + 1 * HWSZ + offD);
    an[7] = uload4(ab + 0 * HWSZ + offD + 1);

    v4 dc[8], dn[8];
#pragma unroll
    for (int c = 0; c < 8; ++c) dc[c] = aload4(db + c * HWSZ + offC);
    dn[0] = uload4(db + 7 * HWSZ + offU - 1);
    dn[1] = aload4(db + 6 * HWSZ + offU);
    dn[2] = uload4(db + 5 * HWSZ + offU + 1);
    dn[3] = uload4(db + 4 * HWSZ + offC - 1);
    dn[4] = uload4(db + 3 * HWSZ + offC + 1);
    dn[5] = uload4(db + 2 * HWSZ + offD - 1);
    dn[6] = aload4(db + 1 * HWSZ + offD);
    dn[7] = uload4(db + 0 * HWSZ + offD + 1);

    uint32_t sel = 0u;
#pragma unroll
    for (int c = 0; c < 8; ++c)
#pragma unroll
        for (int i = 0; i < 4; ++i)
            if (cvv[c][i] > 0.5f) sel |= (1u << (c * 4 + i));
    uint32_t tb = 0u;
#pragma unroll
    for (int i = 0; i < 4; ++i)
        if (tv[i] > 0.5f) tb |= (1u << i);

    const float mkA[8] = {mh0 * mw0, mh0, mh0,       mw0, 1.f, mh1 * mw0, mh1, mh1};
    const float mkB[8] = {mh0,       mh0, mh0,       1.f, 1.f, mh1,       mh1, mh1};
    const float mkC[8] = {mh0,       mh0, mh0 * mw3, 1.f, mw3, mh1,       mh1, mh1 * mw3};

    v4 glo1, glo2, vmin1, vmin2;
    float Lb1, Lc1, Lb2, Lc2;
    eval_branch<false>(ac, an, sel, mkA, mkB, mkC, glo1, vmin1, Lb1, Lc1);
    eval_branch<true >(dc, dn, sel, mkA, mkB, mkC, glo2, vmin2, Lb2, Lc2);

    // pixel-level: bce(glo1,t) + bce(dec,t), combined into one log
    float Lp = 0.f;
#pragma unroll
    for (int i = 0; i < 4; ++i) {
        const uint32_t mI    = 0x11111111u << i;
        const uint32_t bitsI = sel & mI;
        const bool edge = (bitsI != 0u) && (bitsI != mI);   // 0 < popcount < 8
        const float dec = edge ? (1.0f - vmin2[i]) : glo2[i];
        const bool  ti  = (tb >> i) & 1u;
        const float a   = ti ? glo1[i] : 1.0f - glo1[i];
        const float bs  = ti ? dec     : 1.0f - dec;
        Lp += fmaxf(__log2f(a * bs), LOG2_CLAMP);
    }

    const float wbic = 0.2f / (float)(BB * CC * HWSZ);
    const float wcon = 0.8f / (float)(BB * CC * HWSZ);
    const float wpix = 1.0f / (float)(BB * HWSZ);
    const float ln2  = 0.69314718056f;

    float local = -(wbic * (Lb1 + Lb2) + wcon * (Lc1 + Lc2) + wpix * Lp) * ln2;

#pragma unroll
    for (int off = 32; off > 0; off >>= 1)
        local += __shfl_down(local, off, 64);

    __shared__ float wsum[4];
    const int lane = threadIdx.x & 63;
    const int wid  = threadIdx.x >> 6;
    if (lane == 0) wsum[wid] = local;
    __syncthreads();
    // ONE plain store per block to its OWN slot — no same-line atomic RMW chain.
    if (threadIdx.x == 0)
        partial[blockIdx.x] = wsum[0] + wsum[1] + wsum[2] + wsum[3];
}

// 2048 partials -> out, single block (launch-latency dominated, ~3-4 us)
__global__ __launch_bounds__(256, 1) void reduce_kernel(
    const float* __restrict__ partial, float* __restrict__ out)
{
    const int tid = (int)threadIdx.x;
    float s = 0.f;
#pragma unroll
    for (int i = 0; i < 8; ++i) s += partial[tid + i * 256];
#pragma unroll
    for (int off = 32; off > 0; off >>= 1)
        s += __shfl_down(s, off, 64);
    __shared__ float ws[4];
    if ((tid & 63) == 0) ws[tid >> 6] = s;
    __syncthreads();
    if (tid == 0) out[0] = ws[0] + ws[1] + ws[2] + ws[3];
}

extern "C" void kernel_launch(void* const* d_in, const int* in_sizes, int n_in,
                              void* d_out, int out_size, void* d_ws, size_t ws_size,
                              hipStream_t stream) {
    const float* atts   = (const float*)d_in[0];
    const float* dets   = (const float*)d_in[1];
    const float* target = (const float*)d_in[2];
    const float* con    = (const float*)d_in[3];
    float* out     = (float*)d_out;
    float* partial = (float*)d_ws;          // 2048 * 4 B = 8 KiB

    const int nblocks = BB * HH * WW / 4 / 256;   // 2048 blocks
    bicon_loss_kernel<<<nblocks, 256, 0, stream>>>(atts, dets, target, con, partial);
    reduce_kernel<<<1, 256, 0, stream>>>(partial, out);
}